// Round 18
// baseline (178.276 us; speedup 1.0000x reference)
//
#include <hip/hip_runtime.h>
#include <hip/hip_bf16.h>
#include <cstdint>
#include <cstddef>

using bf16 = __bf16;
typedef __attribute__((ext_vector_type(8))) __bf16 bf16x8;
typedef __attribute__((ext_vector_type(4))) float  f32x4;

#define LOG2E 1.4426950408889634f

__device__ inline void gld_lds16(const void* g, void* l) {
  __builtin_amdgcn_global_load_lds(
      (const __attribute__((address_space(1))) void*)g,
      (__attribute__((address_space(3))) void*)l, 16, 0, 0);
}

// ---- fp32 -> bf16 convert, x + all 4 weights in ONE launch (grid 2560) ----
__global__ __launch_bounds__(256) void k_cvt_all(
    const float* __restrict__ x, const float* __restrict__ wq,
    const float* __restrict__ wk, const float* __restrict__ wv,
    const float* __restrict__ wo, bf16* __restrict__ xb,
    bf16* __restrict__ wqkv, bf16* __restrict__ wob) {
  int i = blockIdx.x * 256 + threadIdx.x;  // 0..655359, exact
  const float* s;
  bf16* d;
  int local;
  if (i < 524288) {
    s = x; d = xb; local = i;
  } else {
    int i2 = i - 524288;
    int which = i2 >> 15;
    local = i2 & 32767;
    s = (which == 0) ? wq : (which == 1) ? wk : (which == 2) ? wv : wo;
    d = (which < 3) ? (wqkv + ((size_t)which << 18)) : wob;
  }
  const float4* p = ((const float4*)s) + (size_t)local * 2;
  float4 a = p[0], b = p[1];
  bf16x8 o;
  o[0] = (bf16)a.x; o[1] = (bf16)a.y; o[2] = (bf16)a.z; o[3] = (bf16)a.w;
  o[4] = (bf16)b.x; o[5] = (bf16)b.y; o[6] = (bf16)b.z; o[7] = (bf16)b.w;
  *(bf16x8*)(d + (size_t)local * 8) = o;
}

// ---------------- gemm_bt: C[M,128tile] = A[M,512] * B[N,512]^T ---------------
// 128x128 tile, BK=64, 4 waves (2x2 -> 64x64 per wave), 16x16x32 bf16 MFMA.
// mode 0: QKV fused (grid.y=12); mode 1: out proj (grid.y=4): fp32 + bias
__global__ __launch_bounds__(256) void k_gemm(
    const bf16* __restrict__ A, const bf16* __restrict__ B, int mode,
    bf16* __restrict__ Qb, bf16* __restrict__ Kb, bf16* __restrict__ Vtb,
    float* __restrict__ outf, const float* __restrict__ bias) {
  const int K = 512;
  __shared__ alignas(16) bf16 As[128 * 64];
  __shared__ alignas(16) bf16 Bs[128 * 64];
  const int tid = threadIdx.x;
  const int wave = tid >> 6, lane = tid & 63;
  const int l15 = lane & 15, l4 = lane >> 4;
  const int m0 = blockIdx.x * 128, n0 = blockIdx.y * 128;
  const int wr = wave >> 1, wc = wave & 1;
  f32x4 acc[4][4] = {};

  for (int k0 = 0; k0 < K; k0 += 64) {
#pragma unroll
    for (int it = 0; it < 4; ++it) {
      int c = it * 256 + tid;
      int row = c >> 3, kc = c & 7;
      int sb = (kc * 16) ^ ((row & 7) << 4);
      gld_lds16((const char*)A + ((size_t)(m0 + row) * K + k0) * 2 + sb,
                (char*)As + c * 16);
      gld_lds16((const char*)B + ((size_t)(n0 + row) * K + k0) * 2 + sb,
                (char*)Bs + c * 16);
    }
    __syncthreads();
#pragma unroll
    for (int ks = 0; ks < 2; ++ks) {
      bf16x8 af[4], bff[4];
#pragma unroll
      for (int mf = 0; mf < 4; ++mf) {
        int r = wr * 64 + mf * 16 + l15;
        af[mf] = *(const bf16x8*)((const char*)As + r * 128 +
                                  ((ks * 64 + l4 * 16) ^ ((r & 7) << 4)));
      }
#pragma unroll
      for (int nf = 0; nf < 4; ++nf) {
        int r = wc * 64 + nf * 16 + l15;
        bff[nf] = *(const bf16x8*)((const char*)Bs + r * 128 +
                                   ((ks * 64 + l4 * 16) ^ ((r & 7) << 4)));
      }
#pragma unroll
      for (int mf = 0; mf < 4; ++mf)
#pragma unroll
        for (int nf = 0; nf < 4; ++nf)
          acc[mf][nf] = __builtin_amdgcn_mfma_f32_16x16x32_bf16(
              af[mf], bff[nf], acc[mf][nf], 0, 0, 0);
    }
    __syncthreads();
  }

#pragma unroll
  for (int mf = 0; mf < 4; ++mf)
#pragma unroll
    for (int nf = 0; nf < 4; ++nf)
#pragma unroll
      for (int r = 0; r < 4; ++r) {
        int m = m0 + wr * 64 + mf * 16 + l4 * 4 + r;
        int n = n0 + wc * 64 + nf * 16 + l15;
        float v = acc[mf][nf][r];
        if (mode == 1) {
          outf[(size_t)m * 512 + n] = v + bias[n];
        } else {
          int which = n >> 9, o = n & 511, h = o >> 6, d = o & 63;
          int b = m >> 12, nr = m & 4095;
          if (which == 0)
            Qb[((size_t)(b * 8 + h) * 4096 + nr) * 64 + d] = (bf16)(v * 0.125f);
          else if (which == 1)
            Kb[((size_t)(b * 8 + h) * 4096 + nr) * 64 + d] = (bf16)v;
          else
            Vtb[((size_t)((b * 8 + h) * 64 + d)) * 4096 + nr] = (bf16)v;
        }
      }
}

// ---------------- flash attention core (R14 geometry + safe dbuf) ------------
// Per block: 4 waves x 32 q-rows = 128 q; 2 m-tiles/wave; KV tile 64.
// Double-buffered K/V staging with __syncthreads()-only barriers (race-free):
// per pair {STAGE(buf1,t+1); COMPUTE(buf0,t); sync; STAGE(buf0,t+2);
// COMPUTE(buf1,t+1); sync} -> loads get the full compute phase to land.
// Static buffer offsets via pair-unroll (no runtime-indexed arrays).
// Softmax fixed m=0; denominator via MFMA vs ones; raw v_exp_f32.
// NS=1: full KV, bf16 AO. NS=2: half KV per split (blockIdx.z), fp32 partials.
template <int NS>
__global__ __launch_bounds__(256, 4) void k_attn_t(
    const bf16* __restrict__ Q, const bf16* __restrict__ Kg,
    const bf16* __restrict__ Vt, bf16* __restrict__ AO,
    float* __restrict__ pO, float* __restrict__ pD) {
  __shared__ alignas(16) bf16 Ks[2][64 * 64];    // [buf][kv][d]  16 KiB
  __shared__ alignas(16) bf16 Vs[2][64 * 64];    // [buf][d][kv]  16 KiB
  __shared__ alignas(16) bf16 Ps[4][32 * 64];    // per-wave P    16 KiB
  const int tid = threadIdx.x, wave = tid >> 6, lane = tid & 63;
  const int l15 = lane & 15, l4 = lane >> 4;
  const int bh = blockIdx.y, q0 = blockIdx.x * 128;
  const int z = (NS > 1) ? blockIdx.z : 0;
  const int n_lo = z * (4096 / NS);
  const int NT = 4096 / NS / 64;                 // 64 or 32, always even
  const char* Qb = (const char*)(Q + (size_t)bh * 4096 * 64);
  const char* Kb = (const char*)(Kg + (size_t)bh * 4096 * 64);
  const char* Vb = (const char*)(Vt + (size_t)bh * 64 * 4096);

  // ---- staging: incremented global src pointers, fixed LDS dst ----
  const int c0 = tid, c1 = 256 + tid;
  const int row0 = c0 >> 3, sb0 = ((c0 & 7) * 16) ^ ((row0 & 7) << 4);
  const int row1 = c1 >> 3, sb1 = ((c1 & 7) * 16) ^ ((row1 & 7) << 4);
  const char* ksrc0 = Kb + (size_t)(n_lo + row0) * 128 + sb0;
  const char* ksrc1 = Kb + (size_t)(n_lo + row1) * 128 + sb1;
  const char* vsrc0 = Vb + (size_t)row0 * 8192 + (size_t)n_lo * 2 + sb0;
  const char* vsrc1 = Vb + (size_t)row1 * 8192 + (size_t)n_lo * 2 + sb1;
  char* kdst0 = (char*)Ks + c0 * 16;
  char* kdst1 = (char*)Ks + c1 * 16;
  char* vdst0 = (char*)Vs + c0 * 16;
  char* vdst1 = (char*)Vs + c1 * 16;

  // ---- hoisted tile-invariant LDS fragment pointers (buf0; buf1 = +8192) ----
  const char* kf_p[2][4];  // [ds][cf]
#pragma unroll
  for (int cf = 0; cf < 4; ++cf) {
    int kv = cf * 16 + l15;
#pragma unroll
    for (int ds = 0; ds < 2; ++ds)
      kf_p[ds][cf] = (const char*)Ks + kv * 128 +
                     ((ds * 64 + l4 * 16) ^ ((kv & 7) << 4));
  }
  const char* vf_p[4][2];  // [df][ks]
#pragma unroll
  for (int df = 0; df < 4; ++df) {
    int d = df * 16 + l15;
#pragma unroll
    for (int ks = 0; ks < 2; ++ks)
      vf_p[df][ks] = (const char*)Vs + d * 128 +
                     ((ks * 64 + l4 * 16) ^ ((d & 7) << 4));
  }
  char* pw_p[4][4];  // [r][cf] P-write, m-tile 0 (m-tile 1 = +2048 imm)
#pragma unroll
  for (int r = 0; r < 4; ++r) {
    int q = l4 * 4 + r;
#pragma unroll
    for (int cf = 0; cf < 4; ++cf)
      pw_p[r][cf] = (char*)Ps[wave] + q * 128 +
                    (((cf * 16 + l15) * 2) ^ ((q & 7) << 4));
  }
  const char* pf_p[2];  // [ks] P-read, m-tile 0 (m-tile 1 = +2048 imm)
#pragma unroll
  for (int ks = 0; ks < 2; ++ks)
    pf_p[ks] = (const char*)Ps[wave] + l15 * 128 +
               ((ks * 64 + l4 * 16) ^ ((l15 & 7) << 4));

  // Q fragments (A-operand: m=l15, k=(l4*8..+8)+ds*32), two m-tiles
  bf16x8 qf[2][2];
#pragma unroll
  for (int mrow = 0; mrow < 2; ++mrow)
#pragma unroll
    for (int ds = 0; ds < 2; ++ds)
      qf[mrow][ds] = *(const bf16x8*)(Qb +
          ((size_t)(q0 + wave * 32 + mrow * 16 + l15) * 64 + ds * 32 + l4 * 8) * 2);

  bf16x8 vone;
#pragma unroll
  for (int j = 0; j < 8; ++j) vone[j] = (bf16)1.0f;

  f32x4 oacc[2][4] = {};
  f32x4 dacc[2] = {};

#define STAGE(BO)                                                             \
  do {                                                                        \
    gld_lds16(ksrc0, kdst0 + (BO));                                           \
    gld_lds16(vsrc0, vdst0 + (BO));                                           \
    gld_lds16(ksrc1, kdst1 + (BO));                                           \
    gld_lds16(vsrc1, vdst1 + (BO));                                           \
    ksrc0 += 8192; ksrc1 += 8192;                                             \
    vsrc0 += 128;  vsrc1 += 128;                                              \
  } while (0)

#define COMPUTE(BO)                                                           \
  do {                                                                        \
    f32x4 s[2][4];                                                            \
    _Pragma("unroll")                                                         \
    for (int cf = 0; cf < 4; ++cf) {                                          \
      bf16x8 kf0 = *(const bf16x8*)(kf_p[0][cf] + (BO));                      \
      bf16x8 kf1 = *(const bf16x8*)(kf_p[1][cf] + (BO));                      \
      _Pragma("unroll")                                                       \
      for (int mrow = 0; mrow < 2; ++mrow) {                                  \
        f32x4 z2 = {};                                                        \
        z2 = __builtin_amdgcn_mfma_f32_16x16x32_bf16(qf[mrow][0], kf0, z2,    \
                                                     0, 0, 0);                \
        z2 = __builtin_amdgcn_mfma_f32_16x16x32_bf16(qf[mrow][1], kf1, z2,    \
                                                     0, 0, 0);                \
        s[mrow][cf] = z2;                                                     \
      }                                                                       \
    }                                                                         \
    _Pragma("unroll")                                                         \
    for (int mrow = 0; mrow < 2; ++mrow)                                      \
      _Pragma("unroll")                                                       \
      for (int r = 0; r < 4; ++r)                                             \
        _Pragma("unroll")                                                     \
        for (int cf = 0; cf < 4; ++cf) {                                      \
          float p = __builtin_amdgcn_exp2f(s[mrow][cf][r] * LOG2E);           \
          *(bf16*)(pw_p[r][cf] + mrow * 2048) = (bf16)p;                      \
        }                                                                     \
    bf16x8 pf[2][2];                                                          \
    _Pragma("unroll")                                                         \
    for (int mrow = 0; mrow < 2; ++mrow) {                                    \
      pf[mrow][0] = *(const bf16x8*)(pf_p[0] + mrow * 2048);                  \
      pf[mrow][1] = *(const bf16x8*)(pf_p[1] + mrow * 2048);                  \
    }                                                                         \
    _Pragma("unroll")                                                         \
    for (int mrow = 0; mrow < 2; ++mrow) {                                    \
      dacc[mrow] = __builtin_amdgcn_mfma_f32_16x16x32_bf16(                   \
          pf[mrow][0], vone, dacc[mrow], 0, 0, 0);                            \
      dacc[mrow] = __builtin_amdgcn_mfma_f32_16x16x32_bf16(                   \
          pf[mrow][1], vone, dacc[mrow], 0, 0, 0);                            \
    }                                                                         \
    _Pragma("unroll")                                                         \
    for (int df = 0; df < 4; ++df) {                                          \
      bf16x8 vf0 = *(const bf16x8*)(vf_p[df][0] + (BO));                      \
      bf16x8 vf1 = *(const bf16x8*)(vf_p[df][1] + (BO));                      \
      _Pragma("unroll")                                                       \
      for (int mrow = 0; mrow < 2; ++mrow) {                                  \
        oacc[mrow][df] = __builtin_amdgcn_mfma_f32_16x16x32_bf16(             \
            pf[mrow][0], vf0, oacc[mrow][df], 0, 0, 0);                       \
        oacc[mrow][df] = __builtin_amdgcn_mfma_f32_16x16x32_bf16(             \
            pf[mrow][1], vf1, oacc[mrow][df], 0, 0, 0);                       \
      }                                                                       \
    }                                                                         \
  } while (0)

  // prologue: tile 0 -> buf0
  STAGE(0);
  __syncthreads();  // implicit vmcnt(0) drain: buf0 ready

  const int NP = NT / 2;
  for (int p = 0; p < NP; ++p) {
    // tile 2p in buf0; issue tile 2p+1 -> buf1 first (lands during compute)
    STAGE(8192);
    COMPUTE(0);
    __syncthreads();  // buf1 ready; all waves done reading buf0
    // tile 2p+1 in buf1; issue tile 2p+2 -> buf0 if it exists
    if (p + 1 < NP) STAGE(0);
    COMPUTE(8192);
    __syncthreads();  // buf0 ready; all waves done reading buf1
  }
#undef STAGE
#undef COMPUTE

  if (NS > 1) {
    float* po = pO + (((size_t)(z * 16 + bh)) * 4096) * 64;
    float* pd = pD + ((size_t)(z * 16 + bh)) * 4096;
#pragma unroll
    for (int mrow = 0; mrow < 2; ++mrow)
#pragma unroll
      for (int r = 0; r < 4; ++r) {
        int n = q0 + wave * 32 + mrow * 16 + l4 * 4 + r;
#pragma unroll
        for (int df = 0; df < 4; ++df)
          po[(size_t)n * 64 + df * 16 + l15] = oacc[mrow][df][r];
        if (l15 == 0) pd[n] = dacc[mrow][r];
      }
  } else {
    int b = bh >> 3, h = bh & 7;
#pragma unroll
    for (int mrow = 0; mrow < 2; ++mrow)
#pragma unroll
      for (int r = 0; r < 4; ++r) {
        float inv = 1.0f / dacc[mrow][r];
        int n = q0 + wave * 32 + mrow * 16 + l4 * 4 + r;
#pragma unroll
        for (int df = 0; df < 4; ++df) {
          int d = df * 16 + l15;
          AO[((size_t)(b * 4096 + n)) * 512 + h * 64 + d] =
              (bf16)(oacc[mrow][df][r] * inv);
        }
      }
  }
}

// combine: AO[bh,q,:] = (pO[0]+pO[1]) / (pD[0]+pD[1]); 8 d's per thread
__global__ __launch_bounds__(256) void k_comb(
    const float* __restrict__ pO, const float* __restrict__ pD,
    bf16* __restrict__ AO) {
  const size_t SO = (size_t)16 * 4096 * 64;  // split stride in pO
  const size_t SD = (size_t)16 * 4096;       // split stride in pD
  int i = blockIdx.x * 256 + threadIdx.x;    // 0..524287
  int g = i >> 3, j = i & 7;                 // g = bh*4096+n, j = d-octet
  float den = pD[g] + pD[g + SD];
  float inv = 1.0f / den;
  const float* a = pO + (size_t)g * 64 + j * 8;
  const float* b2 = a + SO;
  bf16x8 o;
#pragma unroll
  for (int t = 0; t < 8; ++t) o[t] = (bf16)((a[t] + b2[t]) * inv);
  int bh = g >> 12, n = g & 4095, b = bh >> 3, h = bh & 7;
  *(bf16x8*)(AO + ((size_t)(b * 4096 + n)) * 512 + h * 64 + j * 8) = o;
}

extern "C" void kernel_launch(void* const* d_in, const int* in_sizes, int n_in,
                              void* d_out, int out_size, void* d_ws,
                              size_t ws_size, hipStream_t stream) {
  const float* x  = (const float*)d_in[0];
  const float* Wq = (const float*)d_in[1];
  const float* Wk = (const float*)d_in[2];
  const float* Wv = (const float*)d_in[3];
  const float* Wo = (const float*)d_in[4];
  const float* bo = (const float*)d_in[5];
  float* out = (float*)d_out;

  char* ws = (char*)d_ws;
  bf16* xb   = (bf16*)(ws);                                // 8 MiB
  bf16* wqkv = (bf16*)(ws + (8u << 20));                   // 1.5 MiB [1536,512]
  bf16* wob  = (bf16*)(ws + (8u << 20) + 1572864u);        // 0.5 MiB
  bf16* Qb   = (bf16*)(ws + (10u << 20));                  // 8 MiB [16,4096,64]
  bf16* Kb   = (bf16*)(ws + (18u << 20));                  // 8 MiB [16,4096,64]
  bf16* Vtb  = (bf16*)(ws + (26u << 20));                  // 8 MiB [16,64,4096]
  bf16* AOb  = (bf16*)(ws + (34u << 20));                  // 8 MiB [8192,512]
  float* pD  = (float*)(ws + (42u << 20));                 // 0.5 MiB x2 splits
  float* pO  = (float*)(ws + (43u << 20));                 // 32 MiB (2 splits)

  k_cvt_all<<<2560, 256, 0, stream>>>(x, Wq, Wk, Wv, Wo, xb, wqkv, wob);

  k_gemm<<<dim3(64, 12), 256, 0, stream>>>(xb, wqkv, 0, Qb, Kb, Vtb,
                                           nullptr, nullptr);

  if (ws_size >= ((size_t)75 << 20)) {
    k_attn_t<2><<<dim3(32, 16, 2), 256, 0, stream>>>(Qb, Kb, Vtb, nullptr,
                                                     pO, pD);
    k_comb<<<2048, 256, 0, stream>>>(pO, pD, AOb);
  } else {
    k_attn_t<1><<<dim3(32, 16), 256, 0, stream>>>(Qb, Kb, Vtb, AOb,
                                                  nullptr, nullptr);
  }

  k_gemm<<<dim3(64, 4), 256, 0, stream>>>(AOb, wob, 1, nullptr, nullptr,
                                          nullptr, out, bo);
}

// Round 19
// 161.146 us; speedup vs baseline: 1.1063x; 1.1063x over previous
//
#include <hip/hip_runtime.h>
#include <hip/hip_bf16.h>
#include <cstdint>
#include <cstddef>

using bf16 = __bf16;
typedef __attribute__((ext_vector_type(8))) __bf16 bf16x8;
typedef __attribute__((ext_vector_type(4))) float  f32x4;

#define LOG2E 1.4426950408889634f

__device__ inline void gld_lds16(const void* g, void* l) {
  __builtin_amdgcn_global_load_lds(
      (const __attribute__((address_space(1))) void*)g,
      (__attribute__((address_space(3))) void*)l, 16, 0, 0);
}

// ---- fp32 -> bf16 convert, x + all 4 weights in ONE launch (grid 2560) ----
__global__ __launch_bounds__(256) void k_cvt_all(
    const float* __restrict__ x, const float* __restrict__ wq,
    const float* __restrict__ wk, const float* __restrict__ wv,
    const float* __restrict__ wo, bf16* __restrict__ xb,
    bf16* __restrict__ wqkv, bf16* __restrict__ wob) {
  int i = blockIdx.x * 256 + threadIdx.x;  // 0..655359, exact
  const float* s;
  bf16* d;
  int local;
  if (i < 524288) {
    s = x; d = xb; local = i;
  } else {
    int i2 = i - 524288;
    int which = i2 >> 15;
    local = i2 & 32767;
    s = (which == 0) ? wq : (which == 1) ? wk : (which == 2) ? wv : wo;
    d = (which < 3) ? (wqkv + ((size_t)which << 18)) : wob;
  }
  const float4* p = ((const float4*)s) + (size_t)local * 2;
  float4 a = p[0], b = p[1];
  bf16x8 o;
  o[0] = (bf16)a.x; o[1] = (bf16)a.y; o[2] = (bf16)a.z; o[3] = (bf16)a.w;
  o[4] = (bf16)b.x; o[5] = (bf16)b.y; o[6] = (bf16)b.z; o[7] = (bf16)b.w;
  *(bf16x8*)(d + (size_t)local * 8) = o;
}

// ---------------- gemm_bt: C[M,128tile] = A[M,512] * B[N,512]^T ---------------
// 128x128 tile, BK=64, 4 waves (2x2 -> 64x64 per wave), 16x16x32 bf16 MFMA.
// mode 0: QKV fused (grid.y=12); mode 1: out proj (grid.y=4): fp32 + bias
__global__ __launch_bounds__(256) void k_gemm(
    const bf16* __restrict__ A, const bf16* __restrict__ B, int mode,
    bf16* __restrict__ Qb, bf16* __restrict__ Kb, bf16* __restrict__ Vtb,
    float* __restrict__ outf, const float* __restrict__ bias) {
  const int K = 512;
  __shared__ alignas(16) bf16 As[128 * 64];
  __shared__ alignas(16) bf16 Bs[128 * 64];
  const int tid = threadIdx.x;
  const int wave = tid >> 6, lane = tid & 63;
  const int l15 = lane & 15, l4 = lane >> 4;
  const int m0 = blockIdx.x * 128, n0 = blockIdx.y * 128;
  const int wr = wave >> 1, wc = wave & 1;
  f32x4 acc[4][4] = {};

  for (int k0 = 0; k0 < K; k0 += 64) {
#pragma unroll
    for (int it = 0; it < 4; ++it) {
      int c = it * 256 + tid;
      int row = c >> 3, kc = c & 7;
      int sb = (kc * 16) ^ ((row & 7) << 4);
      gld_lds16((const char*)A + ((size_t)(m0 + row) * K + k0) * 2 + sb,
                (char*)As + c * 16);
      gld_lds16((const char*)B + ((size_t)(n0 + row) * K + k0) * 2 + sb,
                (char*)Bs + c * 16);
    }
    __syncthreads();
#pragma unroll
    for (int ks = 0; ks < 2; ++ks) {
      bf16x8 af[4], bff[4];
#pragma unroll
      for (int mf = 0; mf < 4; ++mf) {
        int r = wr * 64 + mf * 16 + l15;
        af[mf] = *(const bf16x8*)((const char*)As + r * 128 +
                                  ((ks * 64 + l4 * 16) ^ ((r & 7) << 4)));
      }
#pragma unroll
      for (int nf = 0; nf < 4; ++nf) {
        int r = wc * 64 + nf * 16 + l15;
        bff[nf] = *(const bf16x8*)((const char*)Bs + r * 128 +
                                   ((ks * 64 + l4 * 16) ^ ((r & 7) << 4)));
      }
#pragma unroll
      for (int mf = 0; mf < 4; ++mf)
#pragma unroll
        for (int nf = 0; nf < 4; ++nf)
          acc[mf][nf] = __builtin_amdgcn_mfma_f32_16x16x32_bf16(
              af[mf], bff[nf], acc[mf][nf], 0, 0, 0);
    }
    __syncthreads();
  }

#pragma unroll
  for (int mf = 0; mf < 4; ++mf)
#pragma unroll
    for (int nf = 0; nf < 4; ++nf)
#pragma unroll
      for (int r = 0; r < 4; ++r) {
        int m = m0 + wr * 64 + mf * 16 + l4 * 4 + r;
        int n = n0 + wc * 64 + nf * 16 + l15;
        float v = acc[mf][nf][r];
        if (mode == 1) {
          outf[(size_t)m * 512 + n] = v + bias[n];
        } else {
          int which = n >> 9, o = n & 511, h = o >> 6, d = o & 63;
          int b = m >> 12, nr = m & 4095;
          if (which == 0)
            Qb[((size_t)(b * 8 + h) * 4096 + nr) * 64 + d] = (bf16)(v * 0.125f);
          else if (which == 1)
            Kb[((size_t)(b * 8 + h) * 4096 + nr) * 64 + d] = (bf16)v;
          else
            Vtb[((size_t)((b * 8 + h) * 64 + d)) * 4096 + nr] = (bf16)v;
        }
      }
}

// ---------------- flash attention core (R17-proven, XCD-swizzled grid) -------
// Per block: 4 waves x 32 q-rows = 128 q; 2 m-tiles/wave; KV tile 64.
// 1D grid, XCD-aware decode: each XCD owns 2*NS contiguous (bh,z) groups
// (2 bh x NS halves = 2 MB K/V working set -> fits the 4 MiB per-XCD L2),
// so K/V staging reads become L2 hits instead of HBM round-trips.
// K/V fragments loaded once per tile, fed to both m-tiles; m-tile 1's P rows
// at +2048 B, identical XOR swizzle. Softmax fixed m=0; denominator via MFMA
// vs ones; raw v_exp_f32; hoisted tile-invariant LDS pointers.
// NS=1: full KV, bf16 AO (grid 512). NS=2: half KV per split (grid 1024).
template <int NS>
__global__ __launch_bounds__(256, 4) void k_attn_t(
    const bf16* __restrict__ Q, const bf16* __restrict__ Kg,
    const bf16* __restrict__ Vt, bf16* __restrict__ AO,
    float* __restrict__ pO, float* __restrict__ pD) {
  __shared__ alignas(16) bf16 Ks[64 * 64];       // [kv][d]   8 KiB
  __shared__ alignas(16) bf16 Vs[64 * 64];       // [d][kv]   8 KiB
  __shared__ alignas(16) bf16 Ps[4][32 * 64];    // per-wave P, 32 rows  16 KiB
  const int tid = threadIdx.x, wave = tid >> 6, lane = tid & 63;
  const int l15 = lane & 15, l4 = lane >> 4;

  // XCD-aware work decode (bijective: 8 XCD x 2NS groups x 32 q-tiles)
  const int wgid = blockIdx.x;
  const int xcd = wgid & 7;
  const int slot = wgid >> 3;
  const int group = xcd * (2 * NS) + (slot >> 5);  // 0..16*NS-1
  const int qt = slot & 31;
  const int bh = group / NS;
  const int z = group % NS;
  const int q0 = qt * 128;
  const int n_lo = z * (4096 / NS);
  const int NT = 4096 / NS / 64;

  const char* Qb = (const char*)(Q + (size_t)bh * 4096 * 64);
  const char* Kb = (const char*)(Kg + (size_t)bh * 4096 * 64);
  const char* Vb = (const char*)(Vt + (size_t)bh * 64 * 4096);

  // ---- staging: incremented global src pointers, fixed LDS dst ----
  const int c0 = tid, c1 = 256 + tid;
  const int row0 = c0 >> 3, sb0 = ((c0 & 7) * 16) ^ ((row0 & 7) << 4);
  const int row1 = c1 >> 3, sb1 = ((c1 & 7) * 16) ^ ((row1 & 7) << 4);
  const char* ksrc0 = Kb + (size_t)(n_lo + row0) * 128 + sb0;
  const char* ksrc1 = Kb + (size_t)(n_lo + row1) * 128 + sb1;
  const char* vsrc0 = Vb + (size_t)row0 * 8192 + (size_t)n_lo * 2 + sb0;
  const char* vsrc1 = Vb + (size_t)row1 * 8192 + (size_t)n_lo * 2 + sb1;
  char* kdst0 = (char*)Ks + c0 * 16;
  char* kdst1 = (char*)Ks + c1 * 16;
  char* vdst0 = (char*)Vs + c0 * 16;
  char* vdst1 = (char*)Vs + c1 * 16;

  // ---- hoisted tile-invariant LDS fragment pointers (m-tile 0 bases) ----
  const char* kf_p[2][4];  // [ds][cf]
#pragma unroll
  for (int cf = 0; cf < 4; ++cf) {
    int kv = cf * 16 + l15;
#pragma unroll
    for (int ds = 0; ds < 2; ++ds)
      kf_p[ds][cf] = (const char*)Ks + kv * 128 +
                     ((ds * 64 + l4 * 16) ^ ((kv & 7) << 4));
  }
  const char* vf_p[4][2];  // [df][ks]
#pragma unroll
  for (int df = 0; df < 4; ++df) {
    int d = df * 16 + l15;
#pragma unroll
    for (int ks = 0; ks < 2; ++ks)
      vf_p[df][ks] = (const char*)Vs + d * 128 +
                     ((ks * 64 + l4 * 16) ^ ((d & 7) << 4));
  }
  char* pw_p[4][4];  // [r][cf] P-write, m-tile 0 (m-tile 1 = +2048 imm)
#pragma unroll
  for (int r = 0; r < 4; ++r) {
    int q = l4 * 4 + r;
#pragma unroll
    for (int cf = 0; cf < 4; ++cf)
      pw_p[r][cf] = (char*)Ps[wave] + q * 128 +
                    (((cf * 16 + l15) * 2) ^ ((q & 7) << 4));
  }
  const char* pf_p[2];  // [ks] P-read, m-tile 0 (m-tile 1 = +2048 imm)
#pragma unroll
  for (int ks = 0; ks < 2; ++ks)
    pf_p[ks] = (const char*)Ps[wave] + l15 * 128 +
               ((ks * 64 + l4 * 16) ^ ((l15 & 7) << 4));

  // Q fragments (A-operand: m=l15, k=(l4*8..+8)+ds*32), two m-tiles
  bf16x8 qf[2][2];
#pragma unroll
  for (int mrow = 0; mrow < 2; ++mrow)
#pragma unroll
    for (int ds = 0; ds < 2; ++ds)
      qf[mrow][ds] = *(const bf16x8*)(Qb +
          ((size_t)(q0 + wave * 32 + mrow * 16 + l15) * 64 + ds * 32 + l4 * 8) * 2);

  bf16x8 vone;
#pragma unroll
  for (int j = 0; j < 8; ++j) vone[j] = (bf16)1.0f;

  f32x4 oacc[2][4] = {};
  f32x4 dacc[2] = {};

  for (int t = 0; t < NT; ++t) {
    gld_lds16(ksrc0, kdst0);
    gld_lds16(vsrc0, vdst0);
    gld_lds16(ksrc1, kdst1);
    gld_lds16(vsrc1, vdst1);
    ksrc0 += 8192; ksrc1 += 8192;  // next 64 kv rows
    vsrc0 += 128;  vsrc1 += 128;   // next 64 kv cols
    __syncthreads();

    // S = Q K^T: K-frag loaded once, feeds both m-tiles
    f32x4 s[2][4];
#pragma unroll
    for (int cf = 0; cf < 4; ++cf) {
      bf16x8 kf0 = *(const bf16x8*)kf_p[0][cf];
      bf16x8 kf1 = *(const bf16x8*)kf_p[1][cf];
#pragma unroll
      for (int mrow = 0; mrow < 2; ++mrow) {
        f32x4 z2 = {};
        z2 = __builtin_amdgcn_mfma_f32_16x16x32_bf16(qf[mrow][0], kf0, z2, 0, 0, 0);
        z2 = __builtin_amdgcn_mfma_f32_16x16x32_bf16(qf[mrow][1], kf1, z2, 0, 0, 0);
        s[mrow][cf] = z2;
      }
    }

    // p = exp2(s*log2e) via raw v_exp_f32; m-tile 1 at +2048 imm offset
#pragma unroll
    for (int mrow = 0; mrow < 2; ++mrow)
#pragma unroll
      for (int r = 0; r < 4; ++r)
#pragma unroll
        for (int cf = 0; cf < 4; ++cf) {
          float p = __builtin_amdgcn_exp2f(s[mrow][cf][r] * LOG2E);
          *(bf16*)(pw_p[r][cf] + mrow * 2048) = (bf16)p;
        }

    // P fragments (A-operand: m=q=l15, k=kv), both m-tiles
    bf16x8 pf[2][2];
#pragma unroll
    for (int mrow = 0; mrow < 2; ++mrow) {
      pf[mrow][0] = *(const bf16x8*)(pf_p[0] + mrow * 2048);
      pf[mrow][1] = *(const bf16x8*)(pf_p[1] + mrow * 2048);
    }

    // denominators
#pragma unroll
    for (int mrow = 0; mrow < 2; ++mrow) {
      dacc[mrow] = __builtin_amdgcn_mfma_f32_16x16x32_bf16(pf[mrow][0], vone,
                                                           dacc[mrow], 0, 0, 0);
      dacc[mrow] = __builtin_amdgcn_mfma_f32_16x16x32_bf16(pf[mrow][1], vone,
                                                           dacc[mrow], 0, 0, 0);
    }

    // O += P V: V-frag loaded once, feeds both m-tiles
#pragma unroll
    for (int df = 0; df < 4; ++df) {
      bf16x8 vf0 = *(const bf16x8*)vf_p[df][0];
      bf16x8 vf1 = *(const bf16x8*)vf_p[df][1];
#pragma unroll
      for (int mrow = 0; mrow < 2; ++mrow) {
        oacc[mrow][df] = __builtin_amdgcn_mfma_f32_16x16x32_bf16(
            pf[mrow][0], vf0, oacc[mrow][df], 0, 0, 0);
        oacc[mrow][df] = __builtin_amdgcn_mfma_f32_16x16x32_bf16(
            pf[mrow][1], vf1, oacc[mrow][df], 0, 0, 0);
      }
    }
    __syncthreads();
  }

  if (NS > 1) {
    float* po = pO + (((size_t)(z * 16 + bh)) * 4096) * 64;
    float* pd = pD + ((size_t)(z * 16 + bh)) * 4096;
#pragma unroll
    for (int mrow = 0; mrow < 2; ++mrow)
#pragma unroll
      for (int r = 0; r < 4; ++r) {
        int n = q0 + wave * 32 + mrow * 16 + l4 * 4 + r;
#pragma unroll
        for (int df = 0; df < 4; ++df)
          po[(size_t)n * 64 + df * 16 + l15] = oacc[mrow][df][r];
        if (l15 == 0) pd[n] = dacc[mrow][r];
      }
  } else {
    int b = bh >> 3, h = bh & 7;
#pragma unroll
    for (int mrow = 0; mrow < 2; ++mrow)
#pragma unroll
      for (int r = 0; r < 4; ++r) {
        float inv = 1.0f / dacc[mrow][r];
        int n = q0 + wave * 32 + mrow * 16 + l4 * 4 + r;
#pragma unroll
        for (int df = 0; df < 4; ++df) {
          int d = df * 16 + l15;
          AO[((size_t)(b * 4096 + n)) * 512 + h * 64 + d] =
              (bf16)(oacc[mrow][df][r] * inv);
        }
      }
  }
}

// combine: AO[bh,q,:] = (pO[0]+pO[1]) / (pD[0]+pD[1]); 8 d's per thread
__global__ __launch_bounds__(256) void k_comb(
    const float* __restrict__ pO, const float* __restrict__ pD,
    bf16* __restrict__ AO) {
  const size_t SO = (size_t)16 * 4096 * 64;  // split stride in pO
  const size_t SD = (size_t)16 * 4096;       // split stride in pD
  int i = blockIdx.x * 256 + threadIdx.x;    // 0..524287
  int g = i >> 3, j = i & 7;                 // g = bh*4096+n, j = d-octet
  float den = pD[g] + pD[g + SD];
  float inv = 1.0f / den;
  const float* a = pO + (size_t)g * 64 + j * 8;
  const float* b2 = a + SO;
  bf16x8 o;
#pragma unroll
  for (int t = 0; t < 8; ++t) o[t] = (bf16)((a[t] + b2[t]) * inv);
  int bh = g >> 12, n = g & 4095, b = bh >> 3, h = bh & 7;
  *(bf16x8*)(AO + ((size_t)(b * 4096 + n)) * 512 + h * 64 + j * 8) = o;
}

extern "C" void kernel_launch(void* const* d_in, const int* in_sizes, int n_in,
                              void* d_out, int out_size, void* d_ws,
                              size_t ws_size, hipStream_t stream) {
  const float* x  = (const float*)d_in[0];
  const float* Wq = (const float*)d_in[1];
  const float* Wk = (const float*)d_in[2];
  const float* Wv = (const float*)d_in[3];
  const float* Wo = (const float*)d_in[4];
  const float* bo = (const float*)d_in[5];
  float* out = (float*)d_out;

  char* ws = (char*)d_ws;
  bf16* xb   = (bf16*)(ws);                                // 8 MiB
  bf16* wqkv = (bf16*)(ws + (8u << 20));                   // 1.5 MiB [1536,512]
  bf16* wob  = (bf16*)(ws + (8u << 20) + 1572864u);        // 0.5 MiB
  bf16* Qb   = (bf16*)(ws + (10u << 20));                  // 8 MiB [16,4096,64]
  bf16* Kb   = (bf16*)(ws + (18u << 20));                  // 8 MiB [16,4096,64]
  bf16* Vtb  = (bf16*)(ws + (26u << 20));                  // 8 MiB [16,64,4096]
  bf16* AOb  = (bf16*)(ws + (34u << 20));                  // 8 MiB [8192,512]
  float* pD  = (float*)(ws + (42u << 20));                 // 0.5 MiB x2 splits
  float* pO  = (float*)(ws + (43u << 20));                 // 32 MiB (2 splits)

  k_cvt_all<<<2560, 256, 0, stream>>>(x, Wq, Wk, Wv, Wo, xb, wqkv, wob);

  k_gemm<<<dim3(64, 12), 256, 0, stream>>>(xb, wqkv, 0, Qb, Kb, Vtb,
                                           nullptr, nullptr);

  if (ws_size >= ((size_t)75 << 20)) {
    k_attn_t<2><<<1024, 256, 0, stream>>>(Qb, Kb, Vtb, nullptr, pO, pD);
    k_comb<<<2048, 256, 0, stream>>>(pO, pD, AOb);
  } else {
    k_attn_t<1><<<512, 256, 0, stream>>>(Qb, Kb, Vtb, AOb, nullptr, nullptr);
  }

  k_gemm<<<dim3(64, 4), 256, 0, stream>>>(AOb, wob, 1, nullptr, nullptr,
                                          nullptr, out, bo);
}